// Round 10
// baseline (124.198 us; speedup 1.0000x reference)
//
#include <hip/hip_runtime.h>

typedef _Float16 f16;
typedef _Float16 f16x4 __attribute__((ext_vector_type(4)));
typedef _Float16 f16x8 __attribute__((ext_vector_type(8)));
typedef float f32x4 __attribute__((ext_vector_type(4)));

#define B_TOT 16384
#define LAT_  16
#define STY_  64
#define ND_   8

#define ROWS 64            // rows per block, held in LDS through all 8 layers
#define NTHR 512           // 8 waves (2 per SIMD)
#define NBLK 256           // B_TOT / ROWS, exactly 1 block/CU

// act LDS geometry: f16 [16 kt][64 row][RSTR], RSTR=40 f16 (80 B) row stride.
// b128 af reads: 16-lane quarters hit each bank exactly 2x (2-way = free).
#define RSTR 40
#define SLAB (64 * RSTR)   // f16 per kt-slab (2560); 5120 B
#define ACT_LDS (16 * SLAB)

// ---------------- prep: transpose+cast all weights into k-tiled fragment layout -
// dst elem (out-col n, k) -> dst[((k>>5)*NR + n)*32 + (k&31)]   (f16)
// z=0: W0 (16x512, Kpad=32, NR=512); z=1..3: W1..W3 (512x512, NR=512)
// z=4..11: U0; 12..19: U1; 20..27: U2 (512x512, NR=512)
// z=28..35: U3 (512x64, NR=64)
__global__ void prep_k(const float* W0, f16* Wt0, const float* W1, f16* Wt1,
                       const float* W2, f16* Wt2, const float* W3, f16* Wt3,
                       const float* U0, f16* U0t, const float* U1, f16* U1t,
                       const float* U2, f16* U2t, const float* U3, f16* U3t) {
  int z = blockIdx.z;
  const float* src; f16* dst; int Kin, Nin, Kpad, NR;
  if (z == 0)      { src = W0; dst = Wt0; Kin = 16;  Nin = 512; Kpad = 32;  NR = 512; }
  else if (z == 1) { src = W1; dst = Wt1; Kin = 512; Nin = 512; Kpad = 512; NR = 512; }
  else if (z == 2) { src = W2; dst = Wt2; Kin = 512; Nin = 512; Kpad = 512; NR = 512; }
  else if (z == 3) { src = W3; dst = Wt3; Kin = 512; Nin = 512; Kpad = 512; NR = 512; }
  else if (z < 12) { int d = z - 4;  src = U0 + (long)d * 262144; dst = U0t + (long)d * 262144; Kin = 512; Nin = 512; Kpad = 512; NR = 512; }
  else if (z < 20) { int d = z - 12; src = U1 + (long)d * 262144; dst = U1t + (long)d * 262144; Kin = 512; Nin = 512; Kpad = 512; NR = 512; }
  else if (z < 28) { int d = z - 20; src = U2 + (long)d * 262144; dst = U2t + (long)d * 262144; Kin = 512; Nin = 512; Kpad = 512; NR = 512; }
  else             { int d = z - 28; src = U3 + (long)d * 32768;  dst = U3t + (long)d * 32768;  Kin = 512; Nin = 64;  Kpad = 512; NR = 64; }

  __shared__ float tile[32][33];
  int k0 = blockIdx.y * 32, n0 = blockIdx.x * 32;
  int tx = threadIdx.x, ty = threadIdx.y;  // 32 x 8
  #pragma unroll
  for (int i = 0; i < 32; i += 8) {
    int k = k0 + ty + i, n = n0 + tx;
    tile[ty + i][tx] = (k < Kin && n < Nin) ? src[(long)k * Nin + n] : 0.f;
  }
  __syncthreads();
  #pragma unroll
  for (int i = 0; i < 32; i += 8) {
    int n = n0 + ty + i, k = k0 + tx;
    if (n < NR && k < Kpad)
      dst[(long)(((k >> 5) * NR + n) << 5) | (k & 31)] = (f16)tile[tx][ty + i];
  }
}

// ---------------- bucketing (atomics-free, deterministic) ----------------
#define NT_BUCKET 1024
#define RPT 16

__global__ __launch_bounds__(NT_BUCKET) void bucket_k(const int* __restrict__ y,
                                                      int* __restrict__ offsets,
                                                      int* __restrict__ perm) {
  __shared__ int hist[ND_][NT_BUCKET];
  __shared__ int totals[ND_];
  __shared__ int bases[ND_ + 1];
  int t = threadIdx.x;
  int base = t * RPT;

  #pragma unroll
  for (int d = 0; d < ND_; d++) hist[d][t] = 0;
  int yv[RPT];
  #pragma unroll
  for (int i = 0; i < RPT; i++) {
    yv[i] = y[base + i];
    hist[yv[i]][t]++;
  }
  __syncthreads();

  int wave = t >> 6, lane = t & 63;
  if (wave < ND_) {
    int d = wave;
    int carry = 0;
    for (int c = 0; c < NT_BUCKET; c += 64) {
      int v = hist[d][c + lane];
      int s = v;
      #pragma unroll
      for (int off = 1; off < 64; off <<= 1) {
        int u = __shfl_up(s, off, 64);
        if (lane >= off) s += u;
      }
      hist[d][c + lane] = carry + s - v;   // exclusive prefix
      carry += __shfl(s, 63, 64);
    }
    if (lane == 0) totals[d] = carry;
  }
  __syncthreads();

  if (t == 0) {
    int s = 0;
    #pragma unroll
    for (int d = 0; d < ND_; d++) { bases[d] = s; offsets[d] = s; s += totals[d]; }
    bases[ND_] = s; offsets[ND_] = s;
  }
  __syncthreads();

  #pragma unroll
  for (int i = 0; i < RPT; i++) {
    int d = yv[i];
    int pos = bases[d] + hist[d][t];
    hist[d][t]++;
    perm[pos] = base + i;
  }
}

#define MFMA_(b, a, c) __builtin_amdgcn_mfma_f32_16x16x32_f16((b), (a), (c), 0, 0, 0)

// ---------------- fused layer ----------------
// 8 waves; wave wid owns out-cols [wid*64, wid*64+64) (NF=4), all 64 rows (MF=4).
// Weights k-tiled [KT][NR][32]; bf global->VGPR, 3-buffer, prefetch distance 2.
// af from LDS act, 2-buffer, prefetch distance 1. All indices compile-time (full unroll).
// Swapped mfma(bf, af): lane holds act-row (m*16+lane&15), out-cols wn+n*16+(lane>>4)*4+j.
template<int KT, bool FINAL>
__device__ __forceinline__ void do_layer(
    const f16* __restrict__ Wk, const float* __restrict__ bias,
    f16* __restrict__ act, int rlo, int rhi,
    const int* __restrict__ perm, int slot0, float* __restrict__ out, int t) {
  const int lane = t & 63, wid = t >> 6;
  const int lr = lane & 15, lg = lane >> 4;
  char* actb = (char*)act;

  __syncthreads();                       // previous layer's act writes visible

  if (!FINAL) {
    const int wn = wid * 64;
    const f16* wp[4];
    #pragma unroll
    for (int n = 0; n < 4; n++)
      wp[n] = Wk + ((wn + n * 16 + lr) * 32 + lg * 8);   // + kt*16384
    const char* ab[4];
    #pragma unroll
    for (int m = 0; m < 4; m++)
      ab[m] = actb + (m * 16 + lr) * 80 + lg * 16;       // + kt*5120

    f32x4 acc[4][4];
    #pragma unroll
    for (int m = 0; m < 4; m++)
      #pragma unroll
      for (int n = 0; n < 4; n++) acc[m][n] = f32x4{0.f, 0.f, 0.f, 0.f};

    f16x8 bf[3][4], af[2][4];
    // prologue: bf for kt=0,1 ; af for kt=0
    #pragma unroll
    for (int n = 0; n < 4; n++) bf[0][n] = *(const f16x8*)(wp[n]);
    if constexpr (KT > 1) {
      #pragma unroll
      for (int n = 0; n < 4; n++) bf[1][n] = *(const f16x8*)(wp[n] + 16384);
    }
    #pragma unroll
    for (int m = 0; m < 4; m++) af[0][m] = *(const f16x8*)(ab[m]);

    #pragma unroll
    for (int kt = 0; kt < KT; kt++) {
      if (kt + 2 < KT) {                 // bf prefetch, distance 2
        #pragma unroll
        for (int n = 0; n < 4; n++)
          bf[(kt + 2) % 3][n] = *(const f16x8*)(wp[n] + (kt + 2) * 16384);
      }
      if (kt + 1 < KT) {                 // af prefetch, distance 1
        #pragma unroll
        for (int m = 0; m < 4; m++)
          af[(kt + 1) % 2][m] = *(const f16x8*)(ab[m] + (kt + 1) * 5120);
      }
      #pragma unroll
      for (int m = 0; m < 4; m++)
        #pragma unroll
        for (int n = 0; n < 4; n++)
          acc[m][n] = MFMA_(bf[kt % 3][n], af[kt % 2][m], acc[m][n]);
    }

    __syncthreads();                     // all af reads done before overwrite

    // epilogue: row r = m*16+lr; global col cn0 = wn + n*16 + lg*4 (+j)
    // act write: slab = 2*wid + (n>>1), within-slab col = (n&1)*16 + lg*4
    #pragma unroll
    for (int m = 0; m < 4; m++) {
      int r = m * 16 + lr;
      bool ok = (r >= rlo) && (r < rhi);
      #pragma unroll
      for (int n = 0; n < 4; n++) {
        int cn0 = wn + n * 16 + lg * 4;
        f32x4 bb = *(const f32x4*)(bias + cn0);
        f16x4 h;
        #pragma unroll
        for (int j = 0; j < 4; j++)
          h[j] = (f16)fmaxf(acc[m][n][j] + bb[j], 0.f);
        int slab = 2 * wid + (n >> 1);
        int cl = (n & 1) * 16 + lg * 4;
        if (ok)
          *(f16x4*)(actb + slab * 5120 + r * 80 + cl * 2) = h;
      }
    }
  } else {
    // final 512->64: wave wid -> rows (wid&3)*16+lr, col-block (wid>>2)*32 (NF=2)
    const int mf = wid & 3, nfb = wid >> 2;
    const f16* wp0 = Wk + ((nfb * 32 + lr) * 32 + lg * 8);        // [kt][64][32]
    const f16* wp1 = Wk + ((nfb * 32 + 16 + lr) * 32 + lg * 8);
    const char* abf = actb + (mf * 16 + lr) * 80 + lg * 16;
    f32x4 a0 = f32x4{0.f, 0.f, 0.f, 0.f}, a1 = a0;
    #pragma unroll
    for (int kt = 0; kt < 16; kt++) {
      f16x8 af = *(const f16x8*)(abf + kt * 5120);
      a0 = MFMA_(*(const f16x8*)(wp0 + kt * 2048), af, a0);
      a1 = MFMA_(*(const f16x8*)(wp1 + kt * 2048), af, a1);
    }
    int r = mf * 16 + lr;
    if (r >= rlo && r < rhi) {
      int orig = perm[slot0 + r];
      int cn0 = nfb * 32 + lg * 4;
      f32x4 bb0 = *(const f32x4*)(bias + cn0);
      f32x4 bb1 = *(const f32x4*)(bias + cn0 + 16);
      f32x4 v0, v1;
      #pragma unroll
      for (int j = 0; j < 4; j++) { v0[j] = a0[j] + bb0[j]; v1[j] = a1[j] + bb1[j]; }
      *(f32x4*)(out + (long)orig * STY_ + cn0) = v0;
      *(f32x4*)(out + (long)orig * STY_ + cn0 + 16) = v1;
    }
  }
}

// ---------------- fused network kernel ----------------
__global__ __launch_bounds__(NTHR, 2) void fused_k(
    const float* __restrict__ x,
    const f16* __restrict__ Wt0, const float* __restrict__ b0,
    const f16* __restrict__ Wt1, const float* __restrict__ b1,
    const f16* __restrict__ Wt2, const float* __restrict__ b2,
    const f16* __restrict__ Wt3, const float* __restrict__ b3,
    const f16* __restrict__ U0t, const float* __restrict__ c0,
    const f16* __restrict__ U1t, const float* __restrict__ c1,
    const f16* __restrict__ U2t, const float* __restrict__ c2,
    const f16* __restrict__ U3t, const float* __restrict__ c3,
    const int* __restrict__ offs, const int* __restrict__ perm,
    float* __restrict__ out) {
  __shared__ f16 act[ACT_LDS];             // [kt][row][40], 80 KB

  int t = threadIdx.x;
  // XCD-chunked bijective swizzle (nwg=256, 8 XCDs)
  int wg = (blockIdx.x & 7) * (NBLK / 8) + (blockIdx.x >> 3);
  int slot0 = wg * ROWS;

  // gather x rows via perm into act slab 0 (cols 16..31 zero)
  char* actb = (char*)act;
  #pragma unroll
  for (int i = 0; i < 4; i++) {
    int e = i * NTHR + t;                  // 0..2047
    int r = e >> 5, c = e & 31;
    int orig = perm[slot0 + r];
    f16 v = (c < LAT_) ? (f16)x[orig * LAT_ + c] : (f16)0.f;
    *(f16*)(actb + r * 80 + c * 2) = v;
  }
  // (do_layer's entry __syncthreads orders these before the first af read)

  // domain span of this block's 64 consecutive slots
  int d0 = 0, d1 = 0;
  #pragma unroll
  for (int d = 1; d < ND_; d++) {
    d0 += (slot0 >= offs[d]);
    d1 += (slot0 + ROWS - 1 >= offs[d]);
  }

  // trunk (shared weights, full row range)
  do_layer<1,  false>(Wt0, b0, act, 0, ROWS, perm, slot0, out, t);
  do_layer<16, false>(Wt1, b1, act, 0, ROWS, perm, slot0, out, t);
  do_layer<16, false>(Wt2, b2, act, 0, ROWS, perm, slot0, out, t);
  do_layer<16, false>(Wt3, b3, act, 0, ROWS, perm, slot0, out, t);

  // experts: boundary blocks (d0<d1) run each layer once per domain, row-masked
  #pragma unroll 1
  for (int d = d0; d <= d1; d++) {
    int rlo = (d == d0) ? 0 : (offs[d] - slot0);
    int rhi = (d == d1) ? ROWS : (offs[d + 1] - slot0);
    do_layer<16, false>(U0t + (long)d * 262144, c0 + d * 512,
                        act, rlo, rhi, perm, slot0, out, t);
  }
  #pragma unroll 1
  for (int d = d0; d <= d1; d++) {
    int rlo = (d == d0) ? 0 : (offs[d] - slot0);
    int rhi = (d == d1) ? ROWS : (offs[d + 1] - slot0);
    do_layer<16, false>(U1t + (long)d * 262144, c1 + d * 512,
                        act, rlo, rhi, perm, slot0, out, t);
  }
  #pragma unroll 1
  for (int d = d0; d <= d1; d++) {
    int rlo = (d == d0) ? 0 : (offs[d] - slot0);
    int rhi = (d == d1) ? ROWS : (offs[d + 1] - slot0);
    do_layer<16, false>(U2t + (long)d * 262144, c2 + d * 512,
                        act, rlo, rhi, perm, slot0, out, t);
  }
  #pragma unroll 1
  for (int d = d0; d <= d1; d++) {
    int rlo = (d == d0) ? 0 : (offs[d] - slot0);
    int rhi = (d == d1) ? ROWS : (offs[d + 1] - slot0);
    do_layer<16, true>(U3t + (long)d * 32768, c3 + d * 64,
                       act, rlo, rhi, perm, slot0, out, t);
  }
}

// ---------------- launch ----------------

extern "C" void kernel_launch(void* const* d_in, const int* in_sizes, int n_in,
                              void* d_out, int out_size, void* d_ws, size_t ws_size,
                              hipStream_t stream) {
  const float* x  = (const float*)d_in[0];
  const int*   y  = (const int*)  d_in[1];
  const float* W0 = (const float*)d_in[2];
  const float* b0 = (const float*)d_in[3];
  const float* W1 = (const float*)d_in[4];
  const float* b1 = (const float*)d_in[5];
  const float* W2 = (const float*)d_in[6];
  const float* b2 = (const float*)d_in[7];
  const float* W3 = (const float*)d_in[8];
  const float* b3 = (const float*)d_in[9];
  const float* U0 = (const float*)d_in[10];
  const float* c0 = (const float*)d_in[11];
  const float* U1 = (const float*)d_in[12];
  const float* c1 = (const float*)d_in[13];
  const float* U2 = (const float*)d_in[14];
  const float* c2 = (const float*)d_in[15];
  const float* U3 = (const float*)d_in[16];
  const float* c3 = (const float*)d_in[17];
  float* out = (float*)d_out;

  char* p = (char*)d_ws;
  auto alloc = [&](size_t bytes) -> char* {
    char* r = p; p += (bytes + 255) & ~(size_t)255; return r;
  };
  f16* Wt0 = (f16*)alloc((size_t)512 * 32 * 2);
  f16* Wt1 = (f16*)alloc((size_t)512 * 512 * 2);
  f16* Wt2 = (f16*)alloc((size_t)512 * 512 * 2);
  f16* Wt3 = (f16*)alloc((size_t)512 * 512 * 2);
  f16* U0t = (f16*)alloc((size_t)ND_ * 512 * 512 * 2);
  f16* U1t = (f16*)alloc((size_t)ND_ * 512 * 512 * 2);
  f16* U2t = (f16*)alloc((size_t)ND_ * 512 * 512 * 2);
  f16* U3t = (f16*)alloc((size_t)ND_ * 16 * 64 * 32 * 2);
  int* offsets = (int*)alloc((ND_ + 1) * 4);
  int* perm    = (int*)alloc((size_t)B_TOT * 4);

  prep_k<<<dim3(16, 16, 36), dim3(32, 8), 0, stream>>>(W0, Wt0, W1, Wt1, W2, Wt2, W3, Wt3,
                                                       U0, U0t, U1, U1t, U2, U2t, U3, U3t);
  bucket_k<<<1, NT_BUCKET, 0, stream>>>(y, offsets, perm);
  fused_k<<<NBLK, NTHR, 0, stream>>>(x, Wt0, b0, Wt1, b1, Wt2, b2, Wt3, b3,
                                     U0t, c0, U1t, c1, U2t, c2, U3t, c3,
                                     offsets, perm, out);
}

// Round 11
// 114.420 us; speedup vs baseline: 1.0855x; 1.0855x over previous
//
#include <hip/hip_runtime.h>

typedef _Float16 f16;
typedef _Float16 f16x4 __attribute__((ext_vector_type(4)));
typedef _Float16 f16x8 __attribute__((ext_vector_type(8)));
typedef float f32x4 __attribute__((ext_vector_type(4)));

#define B_TOT 16384
#define LAT_  16
#define STY_  64
#define ND_   8

#define ROWS 64            // rows per block, held in LDS through all 8 layers
#define NTHR 1024          // 16 waves (4 per SIMD)
#define NBLK 256           // B_TOT / ROWS, exactly 1 block/CU

// act LDS geometry: f16 [16 kt][64 row][RSTR], RSTR=40 f16 (80 B) row stride.
// b128 af reads: per 16-lane quarter, bank starts (20*lr+4*lg)%32 have period 8
// -> 2 lanes/start = 2-way aliasing = free (m136).
#define RSTR 40
#define SLAB (64 * RSTR)   // f16 per kt-slab (2560); 5120 B
#define ACT_LDS (16 * SLAB)

// ---------------- prep: transpose+cast all weights into k-tiled fragment layout -
// dst elem (out-col n, k) -> dst[((k>>5)*NR + n)*32 + (k&31)]   (f16)
// z=0: W0 (16x512, Kpad=32, NR=512); z=1..3: W1..W3 (512x512, NR=512)
// z=4..11: U0; 12..19: U1; 20..27: U2 (512x512, NR=512)
// z=28..35: U3 (512x64, NR=64)
__global__ void prep_k(const float* W0, f16* Wt0, const float* W1, f16* Wt1,
                       const float* W2, f16* Wt2, const float* W3, f16* Wt3,
                       const float* U0, f16* U0t, const float* U1, f16* U1t,
                       const float* U2, f16* U2t, const float* U3, f16* U3t) {
  int z = blockIdx.z;
  const float* src; f16* dst; int Kin, Nin, Kpad, NR;
  if (z == 0)      { src = W0; dst = Wt0; Kin = 16;  Nin = 512; Kpad = 32;  NR = 512; }
  else if (z == 1) { src = W1; dst = Wt1; Kin = 512; Nin = 512; Kpad = 512; NR = 512; }
  else if (z == 2) { src = W2; dst = Wt2; Kin = 512; Nin = 512; Kpad = 512; NR = 512; }
  else if (z == 3) { src = W3; dst = Wt3; Kin = 512; Nin = 512; Kpad = 512; NR = 512; }
  else if (z < 12) { int d = z - 4;  src = U0 + (long)d * 262144; dst = U0t + (long)d * 262144; Kin = 512; Nin = 512; Kpad = 512; NR = 512; }
  else if (z < 20) { int d = z - 12; src = U1 + (long)d * 262144; dst = U1t + (long)d * 262144; Kin = 512; Nin = 512; Kpad = 512; NR = 512; }
  else if (z < 28) { int d = z - 20; src = U2 + (long)d * 262144; dst = U2t + (long)d * 262144; Kin = 512; Nin = 512; Kpad = 512; NR = 512; }
  else             { int d = z - 28; src = U3 + (long)d * 32768;  dst = U3t + (long)d * 32768;  Kin = 512; Nin = 64;  Kpad = 512; NR = 64; }

  __shared__ float tile[32][33];
  int k0 = blockIdx.y * 32, n0 = blockIdx.x * 32;
  int tx = threadIdx.x, ty = threadIdx.y;  // 32 x 8
  #pragma unroll
  for (int i = 0; i < 32; i += 8) {
    int k = k0 + ty + i, n = n0 + tx;
    tile[ty + i][tx] = (k < Kin && n < Nin) ? src[(long)k * Nin + n] : 0.f;
  }
  __syncthreads();
  #pragma unroll
  for (int i = 0; i < 32; i += 8) {
    int n = n0 + ty + i, k = k0 + tx;
    if (n < NR && k < Kpad)
      dst[(long)(((k >> 5) * NR + n) << 5) | (k & 31)] = (f16)tile[tx][ty + i];
  }
}

// ---------------- bucketing (atomics-free, deterministic) ----------------
#define NT_BUCKET 1024
#define RPT 16

__global__ __launch_bounds__(NT_BUCKET) void bucket_k(const int* __restrict__ y,
                                                      int* __restrict__ offsets,
                                                      int* __restrict__ perm) {
  __shared__ int hist[ND_][NT_BUCKET];
  __shared__ int totals[ND_];
  __shared__ int bases[ND_ + 1];
  int t = threadIdx.x;
  int base = t * RPT;

  #pragma unroll
  for (int d = 0; d < ND_; d++) hist[d][t] = 0;
  int yv[RPT];
  #pragma unroll
  for (int i = 0; i < RPT; i++) {
    yv[i] = y[base + i];
    hist[yv[i]][t]++;
  }
  __syncthreads();

  int wave = t >> 6, lane = t & 63;
  if (wave < ND_) {
    int d = wave;
    int carry = 0;
    for (int c = 0; c < NT_BUCKET; c += 64) {
      int v = hist[d][c + lane];
      int s = v;
      #pragma unroll
      for (int off = 1; off < 64; off <<= 1) {
        int u = __shfl_up(s, off, 64);
        if (lane >= off) s += u;
      }
      hist[d][c + lane] = carry + s - v;   // exclusive prefix
      carry += __shfl(s, 63, 64);
    }
    if (lane == 0) totals[d] = carry;
  }
  __syncthreads();

  if (t == 0) {
    int s = 0;
    #pragma unroll
    for (int d = 0; d < ND_; d++) { bases[d] = s; offsets[d] = s; s += totals[d]; }
    bases[ND_] = s; offsets[ND_] = s;
  }
  __syncthreads();

  #pragma unroll
  for (int i = 0; i < RPT; i++) {
    int d = yv[i];
    int pos = bases[d] + hist[d][t];
    hist[d][t]++;
    perm[pos] = base + i;
  }
}

#define MFMA_(b, a, c) __builtin_amdgcn_mfma_f32_16x16x32_f16((b), (a), (c), 0, 0, 0)

// ---------------- fused layer ----------------
// 16 waves; wave wid owns out-cols [wid*32, wid*32+32) (NF=2), all 64 rows (MF=4).
// Weights k-tiled [KT][NR][32]; bf global->VGPR, 4-buffer, prefetch distance 3
// (~470cy cover at 4 waves/SIMD >= L2 latency). af from LDS act, 2-buffer,
// distance 1 (~156cy >= LDS latency). All indices compile-time (full unroll).
// Swapped mfma(bf, af): lane holds act-row (m*16+lane&15), out-cols wn+n*16+(lane>>4)*4+j.
template<int KT, bool FINAL>
__device__ __forceinline__ void do_layer(
    const f16* __restrict__ Wk, const float* __restrict__ bias,
    f16* __restrict__ act, int rlo, int rhi,
    const int* __restrict__ perm, int slot0, float* __restrict__ out, int t) {
  const int lane = t & 63, wid = t >> 6;
  const int lr = lane & 15, lg = lane >> 4;
  char* actb = (char*)act;

  __syncthreads();                       // previous layer's act writes visible

  if (!FINAL) {
    const int wn = wid * 32;
    const f16* wp[2];
    #pragma unroll
    for (int n = 0; n < 2; n++)
      wp[n] = Wk + ((wn + n * 16 + lr) * 32 + lg * 8);   // + kt*16384
    const char* ab[4];
    #pragma unroll
    for (int m = 0; m < 4; m++)
      ab[m] = actb + (m * 16 + lr) * 80 + lg * 16;       // + kt*5120

    f32x4 acc[4][2];
    #pragma unroll
    for (int m = 0; m < 4; m++) {
      acc[m][0] = f32x4{0.f, 0.f, 0.f, 0.f};
      acc[m][1] = f32x4{0.f, 0.f, 0.f, 0.f};
    }

    f16x8 bf[4][2], af[2][4];
    // prologue: bf for kt=0..2 (distance-3 pipe), af for kt=0
    #pragma unroll
    for (int n = 0; n < 2; n++) bf[0][n] = *(const f16x8*)(wp[n]);
    if constexpr (KT > 1) {
      #pragma unroll
      for (int n = 0; n < 2; n++) bf[1][n] = *(const f16x8*)(wp[n] + 16384);
    }
    if constexpr (KT > 2) {
      #pragma unroll
      for (int n = 0; n < 2; n++) bf[2][n] = *(const f16x8*)(wp[n] + 2 * 16384);
    }
    #pragma unroll
    for (int m = 0; m < 4; m++) af[0][m] = *(const f16x8*)(ab[m]);

    #pragma unroll
    for (int kt = 0; kt < KT; kt++) {
      if (kt + 3 < KT) {                 // bf prefetch, distance 3
        #pragma unroll
        for (int n = 0; n < 2; n++)
          bf[(kt + 3) & 3][n] = *(const f16x8*)(wp[n] + (kt + 3) * 16384);
      }
      if (kt + 1 < KT) {                 // af prefetch, distance 1
        #pragma unroll
        for (int m = 0; m < 4; m++)
          af[(kt + 1) & 1][m] = *(const f16x8*)(ab[m] + (kt + 1) * 5120);
      }
      #pragma unroll
      for (int m = 0; m < 4; m++)
        #pragma unroll
        for (int n = 0; n < 2; n++)
          acc[m][n] = MFMA_(bf[kt & 3][n], af[kt & 1][m], acc[m][n]);
    }

    __syncthreads();                     // all af reads done before overwrite

    // epilogue: row r = m*16+lr; global col cn0 = wn + n*16 + lg*4 (+j)
    // act write: slab = wid, within-slab col cl = n*16 + lg*4
    #pragma unroll
    for (int m = 0; m < 4; m++) {
      int r = m * 16 + lr;
      bool ok = (r >= rlo) && (r < rhi);
      #pragma unroll
      for (int n = 0; n < 2; n++) {
        int cl = n * 16 + lg * 4;
        f32x4 bb = *(const f32x4*)(bias + wn + cl);
        f16x4 h;
        #pragma unroll
        for (int j = 0; j < 4; j++)
          h[j] = (f16)fmaxf(acc[m][n][j] + bb[j], 0.f);
        if (ok)
          *(f16x4*)(actb + wid * 5120 + r * 80 + cl * 2) = h;
      }
    }
  } else {
    // final 512->64: wave wid -> m-frag mf=wid>>2 (rows mf*16+lr), n-frag nf=wid&3
    const int mf = wid >> 2, nf = wid & 3;
    const f16* wp = Wk + ((nf * 16 + lr) * 32 + lg * 8);   // [kt][64][32], stride 2048
    const char* abf = actb + (mf * 16 + lr) * 80 + lg * 16;
    f32x4 a = f32x4{0.f, 0.f, 0.f, 0.f};
    f16x8 wbuf[4], abuf[2];
    wbuf[0] = *(const f16x8*)(wp);
    wbuf[1] = *(const f16x8*)(wp + 2048);
    wbuf[2] = *(const f16x8*)(wp + 2 * 2048);
    abuf[0] = *(const f16x8*)(abf);
    #pragma unroll
    for (int kt = 0; kt < 16; kt++) {
      if (kt + 3 < 16) wbuf[(kt + 3) & 3] = *(const f16x8*)(wp + (kt + 3) * 2048);
      if (kt + 1 < 16) abuf[(kt + 1) & 1] = *(const f16x8*)(abf + (kt + 1) * 5120);
      a = MFMA_(wbuf[kt & 3], abuf[kt & 1], a);
    }
    int r = mf * 16 + lr;
    if (r >= rlo && r < rhi) {
      int orig = perm[slot0 + r];
      int cn0 = nf * 16 + lg * 4;
      f32x4 bb = *(const f32x4*)(bias + cn0);
      f32x4 v;
      #pragma unroll
      for (int j = 0; j < 4; j++) v[j] = a[j] + bb[j];
      *(f32x4*)(out + (long)orig * STY_ + cn0) = v;
    }
  }
}

// ---------------- fused network kernel ----------------
__global__ __launch_bounds__(NTHR, 4) void fused_k(
    const float* __restrict__ x,
    const f16* __restrict__ Wt0, const float* __restrict__ b0,
    const f16* __restrict__ Wt1, const float* __restrict__ b1,
    const f16* __restrict__ Wt2, const float* __restrict__ b2,
    const f16* __restrict__ Wt3, const float* __restrict__ b3,
    const f16* __restrict__ U0t, const float* __restrict__ c0,
    const f16* __restrict__ U1t, const float* __restrict__ c1,
    const f16* __restrict__ U2t, const float* __restrict__ c2,
    const f16* __restrict__ U3t, const float* __restrict__ c3,
    const int* __restrict__ offs, const int* __restrict__ perm,
    float* __restrict__ out) {
  __shared__ f16 act[ACT_LDS];             // [kt][row][40], 80 KB

  int t = threadIdx.x;
  // XCD-chunked bijective swizzle (nwg=256, 8 XCDs)
  int wg = (blockIdx.x & 7) * (NBLK / 8) + (blockIdx.x >> 3);
  int slot0 = wg * ROWS;

  // gather x rows via perm into act slab 0 (cols 16..31 zero)
  char* actb = (char*)act;
  #pragma unroll
  for (int i = 0; i < 2; i++) {
    int e = i * NTHR + t;                  // 0..2047
    int r = e >> 5, c = e & 31;
    int orig = perm[slot0 + r];
    f16 v = (c < LAT_) ? (f16)x[orig * LAT_ + c] : (f16)0.f;
    *(f16*)(actb + r * 80 + c * 2) = v;
  }
  // (do_layer's entry __syncthreads orders these before the first af read)

  // domain span of this block's 64 consecutive slots
  int d0 = 0, d1 = 0;
  #pragma unroll
  for (int d = 1; d < ND_; d++) {
    d0 += (slot0 >= offs[d]);
    d1 += (slot0 + ROWS - 1 >= offs[d]);
  }

  // trunk (shared weights, full row range)
  do_layer<1,  false>(Wt0, b0, act, 0, ROWS, perm, slot0, out, t);
  do_layer<16, false>(Wt1, b1, act, 0, ROWS, perm, slot0, out, t);
  do_layer<16, false>(Wt2, b2, act, 0, ROWS, perm, slot0, out, t);
  do_layer<16, false>(Wt3, b3, act, 0, ROWS, perm, slot0, out, t);

  // experts: boundary blocks (d0<d1) run each layer once per domain, row-masked
  #pragma unroll 1
  for (int d = d0; d <= d1; d++) {
    int rlo = (d == d0) ? 0 : (offs[d] - slot0);
    int rhi = (d == d1) ? ROWS : (offs[d + 1] - slot0);
    do_layer<16, false>(U0t + (long)d * 262144, c0 + d * 512,
                        act, rlo, rhi, perm, slot0, out, t);
  }
  #pragma unroll 1
  for (int d = d0; d <= d1; d++) {
    int rlo = (d == d0) ? 0 : (offs[d] - slot0);
    int rhi = (d == d1) ? ROWS : (offs[d + 1] - slot0);
    do_layer<16, false>(U1t + (long)d * 262144, c1 + d * 512,
                        act, rlo, rhi, perm, slot0, out, t);
  }
  #pragma unroll 1
  for (int d = d0; d <= d1; d++) {
    int rlo = (d == d0) ? 0 : (offs[d] - slot0);
    int rhi = (d == d1) ? ROWS : (offs[d + 1] - slot0);
    do_layer<16, false>(U2t + (long)d * 262144, c2 + d * 512,
                        act, rlo, rhi, perm, slot0, out, t);
  }
  #pragma unroll 1
  for (int d = d0; d <= d1; d++) {
    int rlo = (d == d0) ? 0 : (offs[d] - slot0);
    int rhi = (d == d1) ? ROWS : (offs[d + 1] - slot0);
    do_layer<16, true>(U3t + (long)d * 32768, c3 + d * 64,
                       act, rlo, rhi, perm, slot0, out, t);
  }
}

// ---------------- launch ----------------

extern "C" void kernel_launch(void* const* d_in, const int* in_sizes, int n_in,
                              void* d_out, int out_size, void* d_ws, size_t ws_size,
                              hipStream_t stream) {
  const float* x  = (const float*)d_in[0];
  const int*   y  = (const int*)  d_in[1];
  const float* W0 = (const float*)d_in[2];
  const float* b0 = (const float*)d_in[3];
  const float* W1 = (const float*)d_in[4];
  const float* b1 = (const float*)d_in[5];
  const float* W2 = (const float*)d_in[6];
  const float* b2 = (const float*)d_in[7];
  const float* W3 = (const float*)d_in[8];
  const float* b3 = (const float*)d_in[9];
  const float* U0 = (const float*)d_in[10];
  const float* c0 = (const float*)d_in[11];
  const float* U1 = (const float*)d_in[12];
  const float* c1 = (const float*)d_in[13];
  const float* U2 = (const float*)d_in[14];
  const float* c2 = (const float*)d_in[15];
  const float* U3 = (const float*)d_in[16];
  const float* c3 = (const float*)d_in[17];
  float* out = (float*)d_out;

  char* p = (char*)d_ws;
  auto alloc = [&](size_t bytes) -> char* {
    char* r = p; p += (bytes + 255) & ~(size_t)255; return r;
  };
  f16* Wt0 = (f16*)alloc((size_t)512 * 32 * 2);
  f16* Wt1 = (f16*)alloc((size_t)512 * 512 * 2);
  f16* Wt2 = (f16*)alloc((size_t)512 * 512 * 2);
  f16* Wt3 = (f16*)alloc((size_t)512 * 512 * 2);
  f16* U0t = (f16*)alloc((size_t)ND_ * 512 * 512 * 2);
  f16* U1t = (f16*)alloc((size_t)ND_ * 512 * 512 * 2);
  f16* U2t = (f16*)alloc((size_t)ND_ * 512 * 512 * 2);
  f16* U3t = (f16*)alloc((size_t)ND_ * 16 * 64 * 32 * 2);
  int* offsets = (int*)alloc((ND_ + 1) * 4);
  int* perm    = (int*)alloc((size_t)B_TOT * 4);

  prep_k<<<dim3(16, 16, 36), dim3(32, 8), 0, stream>>>(W0, Wt0, W1, Wt1, W2, Wt2, W3, Wt3,
                                                       U0, U0t, U1, U1t, U2, U2t, U3, U3t);
  bucket_k<<<1, NT_BUCKET, 0, stream>>>(y, offsets, perm);
  fused_k<<<NBLK, NTHR, 0, stream>>>(x, Wt0, b0, Wt1, b1, Wt2, b2, Wt3, b3,
                                     U0t, c0, U1t, c1, U2t, c2, U3t, c3,
                                     offsets, perm, out);
}

// Round 12
// 113.873 us; speedup vs baseline: 1.0907x; 1.0048x over previous
//
#include <hip/hip_runtime.h>

typedef _Float16 f16;
typedef _Float16 f16x4 __attribute__((ext_vector_type(4)));
typedef _Float16 f16x8 __attribute__((ext_vector_type(8)));
typedef float f32x4 __attribute__((ext_vector_type(4)));

#define B_TOT 16384
#define LAT_  16
#define STY_  64
#define ND_   8

#define ROWS 64            // rows per block, held in LDS through all 8 layers
#define NTHR 1024          // 16 waves (4 per SIMD)
#define NBLK 256           // B_TOT / ROWS, exactly 1 block/CU

// act LDS layout: f16 [16 kt][4 m][4 lg][16 lr][8]  (64 KB, no pad).
// af fragment read (fixed kt,m): lane (lr + 16*lg) reads byte
//   (kt*4+m)*1024 + lg*256 + lr*16  == base + lane*16 -> contiguous 1KB/wave,
// zero bank conflicts (the optimal full-wave b128 pattern).
// Element (row r, col k): byte = ((k>>5)*4 + (r>>4))*1024 + ((k>>3)&3)*256
//                                + (r&15)*16 + (k&7)*2

// ---------------- prep: transpose+cast all weights into k-tiled fragment layout -
// dst elem (out-col n, k) -> dst[((k>>5)*NR + n)*32 + (k&31)]   (f16)
// z=0: W0 (16x512, Kpad=32, NR=512); z=1..3: W1..W3 (512x512, NR=512)
// z=4..11: U0; 12..19: U1; 20..27: U2 (512x512, NR=512)
// z=28..35: U3 (512x64, NR=64)
__global__ void prep_k(const float* W0, f16* Wt0, const float* W1, f16* Wt1,
                       const float* W2, f16* Wt2, const float* W3, f16* Wt3,
                       const float* U0, f16* U0t, const float* U1, f16* U1t,
                       const float* U2, f16* U2t, const float* U3, f16* U3t) {
  int z = blockIdx.z;
  const float* src; f16* dst; int Kin, Nin, Kpad, NR;
  if (z == 0)      { src = W0; dst = Wt0; Kin = 16;  Nin = 512; Kpad = 32;  NR = 512; }
  else if (z == 1) { src = W1; dst = Wt1; Kin = 512; Nin = 512; Kpad = 512; NR = 512; }
  else if (z == 2) { src = W2; dst = Wt2; Kin = 512; Nin = 512; Kpad = 512; NR = 512; }
  else if (z == 3) { src = W3; dst = Wt3; Kin = 512; Nin = 512; Kpad = 512; NR = 512; }
  else if (z < 12) { int d = z - 4;  src = U0 + (long)d * 262144; dst = U0t + (long)d * 262144; Kin = 512; Nin = 512; Kpad = 512; NR = 512; }
  else if (z < 20) { int d = z - 12; src = U1 + (long)d * 262144; dst = U1t + (long)d * 262144; Kin = 512; Nin = 512; Kpad = 512; NR = 512; }
  else if (z < 28) { int d = z - 20; src = U2 + (long)d * 262144; dst = U2t + (long)d * 262144; Kin = 512; Nin = 512; Kpad = 512; NR = 512; }
  else             { int d = z - 28; src = U3 + (long)d * 32768;  dst = U3t + (long)d * 32768;  Kin = 512; Nin = 64;  Kpad = 512; NR = 64; }

  __shared__ float tile[32][33];
  int k0 = blockIdx.y * 32, n0 = blockIdx.x * 32;
  int tx = threadIdx.x, ty = threadIdx.y;  // 32 x 8
  #pragma unroll
  for (int i = 0; i < 32; i += 8) {
    int k = k0 + ty + i, n = n0 + tx;
    tile[ty + i][tx] = (k < Kin && n < Nin) ? src[(long)k * Nin + n] : 0.f;
  }
  __syncthreads();
  #pragma unroll
  for (int i = 0; i < 32; i += 8) {
    int n = n0 + ty + i, k = k0 + tx;
    if (n < NR && k < Kpad)
      dst[(long)(((k >> 5) * NR + n) << 5) | (k & 31)] = (f16)tile[tx][ty + i];
  }
}

// ---------------- bucketing (atomics-free, deterministic) ----------------
#define NT_BUCKET 1024
#define RPT 16

__global__ __launch_bounds__(NT_BUCKET) void bucket_k(const int* __restrict__ y,
                                                      int* __restrict__ offsets,
                                                      int* __restrict__ perm) {
  __shared__ int hist[ND_][NT_BUCKET];
  __shared__ int totals[ND_];
  __shared__ int bases[ND_ + 1];
  int t = threadIdx.x;
  int base = t * RPT;

  #pragma unroll
  for (int d = 0; d < ND_; d++) hist[d][t] = 0;
  int yv[RPT];
  #pragma unroll
  for (int i = 0; i < RPT; i++) {
    yv[i] = y[base + i];
    hist[yv[i]][t]++;
  }
  __syncthreads();

  int wave = t >> 6, lane = t & 63;
  if (wave < ND_) {
    int d = wave;
    int carry = 0;
    for (int c = 0; c < NT_BUCKET; c += 64) {
      int v = hist[d][c + lane];
      int s = v;
      #pragma unroll
      for (int off = 1; off < 64; off <<= 1) {
        int u = __shfl_up(s, off, 64);
        if (lane >= off) s += u;
      }
      hist[d][c + lane] = carry + s - v;   // exclusive prefix
      carry += __shfl(s, 63, 64);
    }
    if (lane == 0) totals[d] = carry;
  }
  __syncthreads();

  if (t == 0) {
    int s = 0;
    #pragma unroll
    for (int d = 0; d < ND_; d++) { bases[d] = s; offsets[d] = s; s += totals[d]; }
    bases[ND_] = s; offsets[ND_] = s;
  }
  __syncthreads();

  #pragma unroll
  for (int i = 0; i < RPT; i++) {
    int d = yv[i];
    int pos = bases[d] + hist[d][t];
    hist[d][t]++;
    perm[pos] = base + i;
  }
}

#define MFMA_(b, a, c) __builtin_amdgcn_mfma_f32_16x16x32_f16((b), (a), (c), 0, 0, 0)

// ---------------- fused layer ----------------
// 16 waves; wave wid owns out-cols [wid*32, wid*32+32) (NF=2), all 64 rows (MF=4).
// Weights k-tiled [KT][NR][32]; bf global->VGPR, 4-buffer, distance 3.
// af from LDS act (contiguous per-wave 1KB reads), 2-buffer, distance 1.
// Swapped mfma(bf, af): lane holds act-row (m*16+lane&15), out-cols wn+n*16+(lane>>4)*4+j.
template<int KT, bool FINAL>
__device__ __forceinline__ void do_layer(
    const f16* __restrict__ Wk, const float* __restrict__ bias,
    f16* __restrict__ act, int rlo, int rhi,
    const int* __restrict__ perm, int slot0, float* __restrict__ out, int t) {
  const int lane = t & 63, wid = t >> 6;
  const int lr = lane & 15, lg = lane >> 4;
  char* actb = (char*)act;

  __syncthreads();                       // previous layer's act writes visible

  if (!FINAL) {
    const int wn = wid * 32;
    const f16* wp[2];
    #pragma unroll
    for (int n = 0; n < 2; n++)
      wp[n] = Wk + ((wn + n * 16 + lr) * 32 + lg * 8);   // + kt*16384
    const char* ab[4];
    #pragma unroll
    for (int m = 0; m < 4; m++)
      ab[m] = actb + m * 1024 + lg * 256 + lr * 16;      // + kt*4096

    f32x4 acc[4][2];
    #pragma unroll
    for (int m = 0; m < 4; m++) {
      acc[m][0] = f32x4{0.f, 0.f, 0.f, 0.f};
      acc[m][1] = f32x4{0.f, 0.f, 0.f, 0.f};
    }

    f16x8 bf[4][2], af[2][4];
    #pragma unroll
    for (int n = 0; n < 2; n++) bf[0][n] = *(const f16x8*)(wp[n]);
    if constexpr (KT > 1) {
      #pragma unroll
      for (int n = 0; n < 2; n++) bf[1][n] = *(const f16x8*)(wp[n] + 16384);
    }
    if constexpr (KT > 2) {
      #pragma unroll
      for (int n = 0; n < 2; n++) bf[2][n] = *(const f16x8*)(wp[n] + 2 * 16384);
    }
    #pragma unroll
    for (int m = 0; m < 4; m++) af[0][m] = *(const f16x8*)(ab[m]);

    #pragma unroll
    for (int kt = 0; kt < KT; kt++) {
      if (kt + 3 < KT) {                 // bf prefetch, distance 3
        #pragma unroll
        for (int n = 0; n < 2; n++)
          bf[(kt + 3) & 3][n] = *(const f16x8*)(wp[n] + (kt + 3) * 16384);
      }
      if (kt + 1 < KT) {                 // af prefetch, distance 1
        #pragma unroll
        for (int m = 0; m < 4; m++)
          af[(kt + 1) & 1][m] = *(const f16x8*)(ab[m] + (kt + 1) * 4096);
      }
      #pragma unroll
      for (int m = 0; m < 4; m++)
        #pragma unroll
        for (int n = 0; n < 2; n++)
          acc[m][n] = MFMA_(bf[kt & 3][n], af[kt & 1][m], acc[m][n]);
    }

    __syncthreads();                     // all af reads done before overwrite

    // epilogue: row r = m*16+lr, out-col cn0 = wn + n*16 + lg*4 (+j, j=0..3)
    // new act byte: kt'=wid, m'=m, lg'=(n*2+(lg>>1)), lr'=lr, e0=(lg&1)*4
    #pragma unroll
    for (int m = 0; m < 4; m++) {
      int r = m * 16 + lr;
      bool ok = (r >= rlo) && (r < rhi);
      #pragma unroll
      for (int n = 0; n < 2; n++) {
        f32x4 bb = *(const f32x4*)(bias + wn + n * 16 + lg * 4);
        f16x4 h;
        #pragma unroll
        for (int j = 0; j < 4; j++)
          h[j] = (f16)fmaxf(acc[m][n][j] + bb[j], 0.f);
        int byte = (wid * 4 + m) * 1024 + (n * 2 + (lg >> 1)) * 256
                 + lr * 16 + (lg & 1) * 8;
        if (ok)
          *(f16x4*)(actb + byte) = h;
      }
    }
  } else {
    // final 512->64: wave wid -> m-frag mf=wid>>2 (rows mf*16+lr), n-frag nf=wid&3
    const int mf = wid >> 2, nf = wid & 3;
    const f16* wp = Wk + ((nf * 16 + lr) * 32 + lg * 8);   // [kt][64][32], stride 2048
    const char* abf = actb + mf * 1024 + lg * 256 + lr * 16;
    f32x4 a = f32x4{0.f, 0.f, 0.f, 0.f};
    f16x8 wbuf[4], abuf[2];
    wbuf[0] = *(const f16x8*)(wp);
    wbuf[1] = *(const f16x8*)(wp + 2048);
    wbuf[2] = *(const f16x8*)(wp + 2 * 2048);
    abuf[0] = *(const f16x8*)(abf);
    #pragma unroll
    for (int kt = 0; kt < 16; kt++) {
      if (kt + 3 < 16) wbuf[(kt + 3) & 3] = *(const f16x8*)(wp + (kt + 3) * 2048);
      if (kt + 1 < 16) abuf[(kt + 1) & 1] = *(const f16x8*)(abf + (kt + 1) * 4096);
      a = MFMA_(wbuf[kt & 3], abuf[kt & 1], a);
    }
    int r = mf * 16 + lr;
    if (r >= rlo && r < rhi) {
      int orig = perm[slot0 + r];
      int cn0 = nf * 16 + lg * 4;
      f32x4 bb = *(const f32x4*)(bias + cn0);
      f32x4 v;
      #pragma unroll
      for (int j = 0; j < 4; j++) v[j] = a[j] + bb[j];
      *(f32x4*)(out + (long)orig * STY_ + cn0) = v;
    }
  }
}

// ---------------- fused network kernel ----------------
__global__ __launch_bounds__(NTHR, 4) void fused_k(
    const float* __restrict__ x,
    const f16* __restrict__ Wt0, const float* __restrict__ b0,
    const f16* __restrict__ Wt1, const float* __restrict__ b1,
    const f16* __restrict__ Wt2, const float* __restrict__ b2,
    const f16* __restrict__ Wt3, const float* __restrict__ b3,
    const f16* __restrict__ U0t, const float* __restrict__ c0,
    const f16* __restrict__ U1t, const float* __restrict__ c1,
    const f16* __restrict__ U2t, const float* __restrict__ c2,
    const f16* __restrict__ U3t, const float* __restrict__ c3,
    const int* __restrict__ offs, const int* __restrict__ perm,
    float* __restrict__ out) {
  __shared__ f16 act[16 * 64 * 32];        // [kt][m][lg][lr][8], 64 KB

  int t = threadIdx.x;
  // XCD-chunked bijective swizzle (nwg=256, 8 XCDs)
  int wg = (blockIdx.x & 7) * (NBLK / 8) + (blockIdx.x >> 3);
  int slot0 = wg * ROWS;

  // gather x rows via perm into act kt=0 (cols 16..31 zero)
  char* actb = (char*)act;
  #pragma unroll
  for (int i = 0; i < 2; i++) {
    int e = i * NTHR + t;                  // 0..2047
    int r = e >> 5, c = e & 31;
    int orig = perm[slot0 + r];
    f16 v = (c < LAT_) ? (f16)x[orig * LAT_ + c] : (f16)0.f;
    int byte = (r >> 4) * 1024 + ((c >> 3) & 3) * 256 + (r & 15) * 16 + (c & 7) * 2;
    *(f16*)(actb + byte) = v;
  }
  // (do_layer's entry __syncthreads orders these before the first af read)

  // domain span of this block's 64 consecutive slots
  int d0 = 0, d1 = 0;
  #pragma unroll
  for (int d = 1; d < ND_; d++) {
    d0 += (slot0 >= offs[d]);
    d1 += (slot0 + ROWS - 1 >= offs[d]);
  }

  // trunk (shared weights, full row range)
  do_layer<1,  false>(Wt0, b0, act, 0, ROWS, perm, slot0, out, t);
  do_layer<16, false>(Wt1, b1, act, 0, ROWS, perm, slot0, out, t);
  do_layer<16, false>(Wt2, b2, act, 0, ROWS, perm, slot0, out, t);
  do_layer<16, false>(Wt3, b3, act, 0, ROWS, perm, slot0, out, t);

  // experts: boundary blocks (d0<d1) run each layer once per domain, row-masked
  #pragma unroll 1
  for (int d = d0; d <= d1; d++) {
    int rlo = (d == d0) ? 0 : (offs[d] - slot0);
    int rhi = (d == d1) ? ROWS : (offs[d + 1] - slot0);
    do_layer<16, false>(U0t + (long)d * 262144, c0 + d * 512,
                        act, rlo, rhi, perm, slot0, out, t);
  }
  #pragma unroll 1
  for (int d = d0; d <= d1; d++) {
    int rlo = (d == d0) ? 0 : (offs[d] - slot0);
    int rhi = (d == d1) ? ROWS : (offs[d + 1] - slot0);
    do_layer<16, false>(U1t + (long)d * 262144, c1 + d * 512,
                        act, rlo, rhi, perm, slot0, out, t);
  }
  #pragma unroll 1
  for (int d = d0; d <= d1; d++) {
    int rlo = (d == d0) ? 0 : (offs[d] - slot0);
    int rhi = (d == d1) ? ROWS : (offs[d + 1] - slot0);
    do_layer<16, false>(U2t + (long)d * 262144, c2 + d * 512,
                        act, rlo, rhi, perm, slot0, out, t);
  }
  #pragma unroll 1
  for (int d = d0; d <= d1; d++) {
    int rlo = (d == d0) ? 0 : (offs[d] - slot0);
    int rhi = (d == d1) ? ROWS : (offs[d + 1] - slot0);
    do_layer<16, true>(U3t + (long)d * 32768, c3 + d * 64,
                       act, rlo, rhi, perm, slot0, out, t);
  }
}

// ---------------- launch ----------------

extern "C" void kernel_launch(void* const* d_in, const int* in_sizes, int n_in,
                              void* d_out, int out_size, void* d_ws, size_t ws_size,
                              hipStream_t stream) {
  const float* x  = (const float*)d_in[0];
  const int*   y  = (const int*)  d_in[1];
  const float* W0 = (const float*)d_in[2];
  const float* b0 = (const float*)d_in[3];
  const float* W1 = (const float*)d_in[4];
  const float* b1 = (const float*)d_in[5];
  const float* W2 = (const float*)d_in[6];
  const float* b2 = (const float*)d_in[7];
  const float* W3 = (const float*)d_in[8];
  const float* b3 = (const float*)d_in[9];
  const float* U0 = (const float*)d_in[10];
  const float* c0 = (const float*)d_in[11];
  const float* U1 = (const float*)d_in[12];
  const float* c1 = (const float*)d_in[13];
  const float* U2 = (const float*)d_in[14];
  const float* c2 = (const float*)d_in[15];
  const float* U3 = (const float*)d_in[16];
  const float* c3 = (const float*)d_in[17];
  float* out = (float*)d_out;

  char* p = (char*)d_ws;
  auto alloc = [&](size_t bytes) -> char* {
    char* r = p; p += (bytes + 255) & ~(size_t)255; return r;
  };
  f16* Wt0 = (f16*)alloc((size_t)512 * 32 * 2);
  f16* Wt1 = (f16*)alloc((size_t)512 * 512 * 2);
  f16* Wt2 = (f16*)alloc((size_t)512 * 512 * 2);
  f16* Wt3 = (f16*)alloc((size_t)512 * 512 * 2);
  f16* U0t = (f16*)alloc((size_t)ND_ * 512 * 512 * 2);
  f16* U1t = (f16*)alloc((size_t)ND_ * 512 * 512 * 2);
  f16* U2t = (f16*)alloc((size_t)ND_ * 512 * 512 * 2);
  f16* U3t = (f16*)alloc((size_t)ND_ * 16 * 64 * 32 * 2);
  int* offsets = (int*)alloc((ND_ + 1) * 4);
  int* perm    = (int*)alloc((size_t)B_TOT * 4);

  prep_k<<<dim3(16, 16, 36), dim3(32, 8), 0, stream>>>(W0, Wt0, W1, Wt1, W2, Wt2, W3, Wt3,
                                                       U0, U0t, U1, U1t, U2, U2t, U3, U3t);
  bucket_k<<<1, NT_BUCKET, 0, stream>>>(y, offsets, perm);
  fused_k<<<NBLK, NTHR, 0, stream>>>(x, Wt0, b0, Wt1, b1, Wt2, b2, Wt3, b3,
                                     U0t, c0, U1t, c1, U2t, c2, U3t, c3,
                                     offsets, perm, out);
}

// Round 13
// 113.619 us; speedup vs baseline: 1.0931x; 1.0022x over previous
//
#include <hip/hip_runtime.h>

typedef _Float16 f16;
typedef _Float16 f16x4 __attribute__((ext_vector_type(4)));
typedef _Float16 f16x8 __attribute__((ext_vector_type(8)));
typedef float f32x4 __attribute__((ext_vector_type(4)));

#define B_TOT 16384
#define LAT_  16
#define STY_  64
#define ND_   8

#define ROWS 64            // rows per block, held in LDS through all 8 layers
#define NTHR 1024          // 16 waves (4 per SIMD)
#define NBLK 256           // B_TOT / ROWS, exactly 1 block/CU

// act LDS layout: f16 [16 kt][4 m][4 lg][16 lr][8]  (64 KB, no pad).
// af fragment read (fixed kt,m): lane (lr + 16*lg) reads byte
//   (kt*4+m)*1024 + lg*256 + lr*16  == base + lane*16 -> contiguous 1KB/wave,
// zero bank conflicts. Element (row r, col k):
//   byte = ((k>>5)*4 + (r>>4))*1024 + ((k>>3)&3)*256 + (r&15)*16 + (k&7)*2

// ---------------- prep: transpose+cast all weights into k-tiled fragment layout -
// dst elem (out-col n, k) -> dst[((k>>5)*NR + n)*32 + (k&31)]   (f16)
__global__ void prep_k(const float* W0, f16* Wt0, const float* W1, f16* Wt1,
                       const float* W2, f16* Wt2, const float* W3, f16* Wt3,
                       const float* U0, f16* U0t, const float* U1, f16* U1t,
                       const float* U2, f16* U2t, const float* U3, f16* U3t) {
  int z = blockIdx.z;
  const float* src; f16* dst; int Kin, Nin, Kpad, NR;
  if (z == 0)      { src = W0; dst = Wt0; Kin = 16;  Nin = 512; Kpad = 32;  NR = 512; }
  else if (z == 1) { src = W1; dst = Wt1; Kin = 512; Nin = 512; Kpad = 512; NR = 512; }
  else if (z == 2) { src = W2; dst = Wt2; Kin = 512; Nin = 512; Kpad = 512; NR = 512; }
  else if (z == 3) { src = W3; dst = Wt3; Kin = 512; Nin = 512; Kpad = 512; NR = 512; }
  else if (z < 12) { int d = z - 4;  src = U0 + (long)d * 262144; dst = U0t + (long)d * 262144; Kin = 512; Nin = 512; Kpad = 512; NR = 512; }
  else if (z < 20) { int d = z - 12; src = U1 + (long)d * 262144; dst = U1t + (long)d * 262144; Kin = 512; Nin = 512; Kpad = 512; NR = 512; }
  else if (z < 28) { int d = z - 20; src = U2 + (long)d * 262144; dst = U2t + (long)d * 262144; Kin = 512; Nin = 512; Kpad = 512; NR = 512; }
  else             { int d = z - 28; src = U3 + (long)d * 32768;  dst = U3t + (long)d * 32768;  Kin = 512; Nin = 64;  Kpad = 512; NR = 64; }

  __shared__ float tile[32][33];
  int k0 = blockIdx.y * 32, n0 = blockIdx.x * 32;
  int tx = threadIdx.x, ty = threadIdx.y;  // 32 x 8
  #pragma unroll
  for (int i = 0; i < 32; i += 8) {
    int k = k0 + ty + i, n = n0 + tx;
    tile[ty + i][tx] = (k < Kin && n < Nin) ? src[(long)k * Nin + n] : 0.f;
  }
  __syncthreads();
  #pragma unroll
  for (int i = 0; i < 32; i += 8) {
    int n = n0 + ty + i, k = k0 + tx;
    if (n < NR && k < Kpad)
      dst[(long)(((k >> 5) * NR + n) << 5) | (k & 31)] = (f16)tile[tx][ty + i];
  }
}

// ---------------- bucketing (atomics-free, deterministic) ----------------
#define NT_BUCKET 1024
#define RPT 16

__global__ __launch_bounds__(NT_BUCKET) void bucket_k(const int* __restrict__ y,
                                                      int* __restrict__ offsets,
                                                      int* __restrict__ perm) {
  __shared__ int hist[ND_][NT_BUCKET];
  __shared__ int totals[ND_];
  __shared__ int bases[ND_ + 1];
  int t = threadIdx.x;
  int base = t * RPT;

  #pragma unroll
  for (int d = 0; d < ND_; d++) hist[d][t] = 0;
  int yv[RPT];
  #pragma unroll
  for (int i = 0; i < RPT; i++) {
    yv[i] = y[base + i];
    hist[yv[i]][t]++;
  }
  __syncthreads();

  int wave = t >> 6, lane = t & 63;
  if (wave < ND_) {
    int d = wave;
    int carry = 0;
    for (int c = 0; c < NT_BUCKET; c += 64) {
      int v = hist[d][c + lane];
      int s = v;
      #pragma unroll
      for (int off = 1; off < 64; off <<= 1) {
        int u = __shfl_up(s, off, 64);
        if (lane >= off) s += u;
      }
      hist[d][c + lane] = carry + s - v;   // exclusive prefix
      carry += __shfl(s, 63, 64);
    }
    if (lane == 0) totals[d] = carry;
  }
  __syncthreads();

  if (t == 0) {
    int s = 0;
    #pragma unroll
    for (int d = 0; d < ND_; d++) { bases[d] = s; offsets[d] = s; s += totals[d]; }
    bases[ND_] = s; offsets[ND_] = s;
  }
  __syncthreads();

  #pragma unroll
  for (int i = 0; i < RPT; i++) {
    int d = yv[i];
    int pos = bases[d] + hist[d][t];
    hist[d][t]++;
    perm[pos] = base + i;
  }
}

#define MFMA_(b, a, c) __builtin_amdgcn_mfma_f32_16x16x32_f16((b), (a), (c), 0, 0, 0)
#define SGB __builtin_amdgcn_sched_group_barrier

// ---------------- fused layer ----------------
// 16 waves; wave wid owns out-cols [wid*32, wid*32+32) (NF=2), all 64 rows (MF=4).
// Weights k-tiled [KT][NR][32]; bf global->VGPR, 4-buffer, distance 3.
// af from LDS act (contiguous per-wave 1KB reads), 2-buffer, distance 1.
// sched_group_barrier pins per-kt issue: [2 VMEM][4 DS_READ][8 MFMA] so the
// compiler cannot collapse the software pipeline (round-11/12 failure mode).
// No barriers in the K-loop -> waves drift -> setprio(1) on MFMA pays (T5).
template<int KT, bool FINAL>
__device__ __forceinline__ void do_layer(
    const f16* __restrict__ Wk, const float* __restrict__ bias,
    f16* __restrict__ act, int rlo, int rhi,
    const int* __restrict__ perm, int slot0, float* __restrict__ out, int t) {
  const int lane = t & 63, wid = t >> 6;
  const int lr = lane & 15, lg = lane >> 4;
  char* actb = (char*)act;

  __syncthreads();                       // previous layer's act writes visible

  if (!FINAL) {
    const int wn = wid * 32;
    const f16* wp[2];
    #pragma unroll
    for (int n = 0; n < 2; n++)
      wp[n] = Wk + ((wn + n * 16 + lr) * 32 + lg * 8);   // + kt*16384
    const char* ab[4];
    #pragma unroll
    for (int m = 0; m < 4; m++)
      ab[m] = actb + m * 1024 + lg * 256 + lr * 16;      // + kt*4096

    f32x4 acc[4][2];
    #pragma unroll
    for (int m = 0; m < 4; m++) {
      acc[m][0] = f32x4{0.f, 0.f, 0.f, 0.f};
      acc[m][1] = f32x4{0.f, 0.f, 0.f, 0.f};
    }

    f16x8 bf[4][2], af[2][4];
    #pragma unroll
    for (int n = 0; n < 2; n++) bf[0][n] = *(const f16x8*)(wp[n]);
    if constexpr (KT > 1) {
      #pragma unroll
      for (int n = 0; n < 2; n++) bf[1][n] = *(const f16x8*)(wp[n] + 16384);
    }
    if constexpr (KT > 2) {
      #pragma unroll
      for (int n = 0; n < 2; n++) bf[2][n] = *(const f16x8*)(wp[n] + 2 * 16384);
    }
    #pragma unroll
    for (int m = 0; m < 4; m++) af[0][m] = *(const f16x8*)(ab[m]);

    #pragma unroll
    for (int kt = 0; kt < KT; kt++) {
      if (kt + 3 < KT) {                 // bf prefetch, distance 3
        #pragma unroll
        for (int n = 0; n < 2; n++)
          bf[(kt + 3) & 3][n] = *(const f16x8*)(wp[n] + (kt + 3) * 16384);
      }
      if (kt + 1 < KT) {                 // af prefetch, distance 1
        #pragma unroll
        for (int m = 0; m < 4; m++)
          af[(kt + 1) & 1][m] = *(const f16x8*)(ab[m] + (kt + 1) * 4096);
      }
      if constexpr (KT > 1) {            // pin per-kt issue pattern
        if (kt + 3 < KT) SGB(0x020, 2, 0);   // 2 global_load (bf kt+3)
        if (kt + 1 < KT) SGB(0x100, 4, 0);   // 4 ds_read (af kt+1)
        SGB(0x008, 8, 0);                    // 8 MFMA (kt)
      }
      __builtin_amdgcn_s_setprio(1);
      #pragma unroll
      for (int m = 0; m < 4; m++)
        #pragma unroll
        for (int n = 0; n < 2; n++)
          acc[m][n] = MFMA_(bf[kt & 3][n], af[kt & 1][m], acc[m][n]);
      __builtin_amdgcn_s_setprio(0);
    }

    __syncthreads();                     // all af reads done before overwrite

    // epilogue: row r = m*16+lr, out-col cn0 = wn + n*16 + lg*4 (+j)
    #pragma unroll
    for (int m = 0; m < 4; m++) {
      int r = m * 16 + lr;
      bool ok = (r >= rlo) && (r < rhi);
      #pragma unroll
      for (int n = 0; n < 2; n++) {
        f32x4 bb = *(const f32x4*)(bias + wn + n * 16 + lg * 4);
        f16x4 h;
        #pragma unroll
        for (int j = 0; j < 4; j++)
          h[j] = (f16)fmaxf(acc[m][n][j] + bb[j], 0.f);
        int byte = (wid * 4 + m) * 1024 + (n * 2 + (lg >> 1)) * 256
                 + lr * 16 + (lg & 1) * 8;
        if (ok)
          *(f16x4*)(actb + byte) = h;
      }
    }
  } else {
    // final 512->64: wave wid -> m-frag mf=wid>>2 (rows mf*16+lr), n-frag nf=wid&3
    const int mf = wid >> 2, nf = wid & 3;
    const f16* wp = Wk + ((nf * 16 + lr) * 32 + lg * 8);   // [kt][64][32], stride 2048
    const char* abf = actb + mf * 1024 + lg * 256 + lr * 16;
    f32x4 a = f32x4{0.f, 0.f, 0.f, 0.f};
    f16x8 wbuf[4], abuf[2];
    wbuf[0] = *(const f16x8*)(wp);
    wbuf[1] = *(const f16x8*)(wp + 2048);
    wbuf[2] = *(const f16x8*)(wp + 2 * 2048);
    abuf[0] = *(const f16x8*)(abf);
    #pragma unroll
    for (int kt = 0; kt < 16; kt++) {
      if (kt + 3 < 16) wbuf[(kt + 3) & 3] = *(const f16x8*)(wp + (kt + 3) * 2048);
      if (kt + 1 < 16) abuf[(kt + 1) & 1] = *(const f16x8*)(abf + (kt + 1) * 4096);
      a = MFMA_(wbuf[kt & 3], abuf[kt & 1], a);
    }
    int r = mf * 16 + lr;
    if (r >= rlo && r < rhi) {
      int orig = perm[slot0 + r];
      int cn0 = nf * 16 + lg * 4;
      f32x4 bb = *(const f32x4*)(bias + cn0);
      f32x4 v;
      #pragma unroll
      for (int j = 0; j < 4; j++) v[j] = a[j] + bb[j];
      *(f32x4*)(out + (long)orig * STY_ + cn0) = v;
    }
  }
}

// ---------------- fused network kernel ----------------
__global__ __launch_bounds__(NTHR, 4) void fused_k(
    const float* __restrict__ x,
    const f16* __restrict__ Wt0, const float* __restrict__ b0,
    const f16* __restrict__ Wt1, const float* __restrict__ b1,
    const f16* __restrict__ Wt2, const float* __restrict__ b2,
    const f16* __restrict__ Wt3, const float* __restrict__ b3,
    const f16* __restrict__ U0t, const float* __restrict__ c0,
    const f16* __restrict__ U1t, const float* __restrict__ c1,
    const f16* __restrict__ U2t, const float* __restrict__ c2,
    const f16* __restrict__ U3t, const float* __restrict__ c3,
    const int* __restrict__ offs, const int* __restrict__ perm,
    float* __restrict__ out) {
  __shared__ f16 act[16 * 64 * 32];        // [kt][m][lg][lr][8], 64 KB

  int t = threadIdx.x;
  // XCD-chunked bijective swizzle (nwg=256, 8 XCDs)
  int wg = (blockIdx.x & 7) * (NBLK / 8) + (blockIdx.x >> 3);
  int slot0 = wg * ROWS;

  // gather x rows via perm into act kt=0 (cols 16..31 zero)
  char* actb = (char*)act;
  #pragma unroll
  for (int i = 0; i < 2; i++) {
    int e = i * NTHR + t;                  // 0..2047
    int r = e >> 5, c = e & 31;
    int orig = perm[slot0 + r];
    f16 v = (c < LAT_) ? (f16)x[orig * LAT_ + c] : (f16)0.f;
    int byte = (r >> 4) * 1024 + ((c >> 3) & 3) * 256 + (r & 15) * 16 + (c & 7) * 2;
    *(f16*)(actb + byte) = v;
  }
  // (do_layer's entry __syncthreads orders these before the first af read)

  // domain span of this block's 64 consecutive slots
  int d0 = 0, d1 = 0;
  #pragma unroll
  for (int d = 1; d < ND_; d++) {
    d0 += (slot0 >= offs[d]);
    d1 += (slot0 + ROWS - 1 >= offs[d]);
  }

  // trunk (shared weights, full row range)
  do_layer<1,  false>(Wt0, b0, act, 0, ROWS, perm, slot0, out, t);
  do_layer<16, false>(Wt1, b1, act, 0, ROWS, perm, slot0, out, t);
  do_layer<16, false>(Wt2, b2, act, 0, ROWS, perm, slot0, out, t);
  do_layer<16, false>(Wt3, b3, act, 0, ROWS, perm, slot0, out, t);

  // experts: boundary blocks (d0<d1) run each layer once per domain, row-masked
  #pragma unroll 1
  for (int d = d0; d <= d1; d++) {
    int rlo = (d == d0) ? 0 : (offs[d] - slot0);
    int rhi = (d == d1) ? ROWS : (offs[d + 1] - slot0);
    do_layer<16, false>(U0t + (long)d * 262144, c0 + d * 512,
                        act, rlo, rhi, perm, slot0, out, t);
  }
  #pragma unroll 1
  for (int d = d0; d <= d1; d++) {
    int rlo = (d == d0) ? 0 : (offs[d] - slot0);
    int rhi = (d == d1) ? ROWS : (offs[d + 1] - slot0);
    do_layer<16, false>(U1t + (long)d * 262144, c1 + d * 512,
                        act, rlo, rhi, perm, slot0, out, t);
  }
  #pragma unroll 1
  for (int d = d0; d <= d1; d++) {
    int rlo = (d == d0) ? 0 : (offs[d] - slot0);
    int rhi = (d == d1) ? ROWS : (offs[d + 1] - slot0);
    do_layer<16, false>(U2t + (long)d * 262144, c2 + d * 512,
                        act, rlo, rhi, perm, slot0, out, t);
  }
  #pragma unroll 1
  for (int d = d0; d <= d1; d++) {
    int rlo = (d == d0) ? 0 : (offs[d] - slot0);
    int rhi = (d == d1) ? ROWS : (offs[d + 1] - slot0);
    do_layer<16, true>(U3t + (long)d * 32768, c3 + d * 64,
                       act, rlo, rhi, perm, slot0, out, t);
  }
}

// ---------------- launch ----------------

extern "C" void kernel_launch(void* const* d_in, const int* in_sizes, int n_in,
                              void* d_out, int out_size, void* d_ws, size_t ws_size,
                              hipStream_t stream) {
  const float* x  = (const float*)d_in[0];
  const int*   y  = (const int*)  d_in[1];
  const float* W0 = (const float*)d_in[2];
  const float* b0 = (const float*)d_in[3];
  const float* W1 = (const float*)d_in[4];
  const float* b1 = (const float*)d_in[5];
  const float* W2 = (const float*)d_in[6];
  const float* b2 = (const float*)d_in[7];
  const float* W3 = (const float*)d_in[8];
  const float* b3 = (const float*)d_in[9];
  const float* U0 = (const float*)d_in[10];
  const float* c0 = (const float*)d_in[11];
  const float* U1 = (const float*)d_in[12];
  const float* c1 = (const float*)d_in[13];
  const float* U2 = (const float*)d_in[14];
  const float* c2 = (const float*)d_in[15];
  const float* U3 = (const float*)d_in[16];
  const float* c3 = (const float*)d_in[17];
  float* out = (float*)d_out;

  char* p = (char*)d_ws;
  auto alloc = [&](size_t bytes) -> char* {
    char* r = p; p += (bytes + 255) & ~(size_t)255; return r;
  };
  f16* Wt0 = (f16*)alloc((size_t)512 * 32 * 2);
  f16* Wt1 = (f16*)alloc((size_t)512 * 512 * 2);
  f16* Wt2 = (f16*)alloc((size_t)512 * 512 * 2);
  f16* Wt3 = (f16*)alloc((size_t)512 * 512 * 2);
  f16* U0t = (f16*)alloc((size_t)ND_ * 512 * 512 * 2);
  f16* U1t = (f16*)alloc((size_t)ND_ * 512 * 512 * 2);
  f16* U2t = (f16*)alloc((size_t)ND_ * 512 * 512 * 2);
  f16* U3t = (f16*)alloc((size_t)ND_ * 16 * 64 * 32 * 2);
  int* offsets = (int*)alloc((ND_ + 1) * 4);
  int* perm    = (int*)alloc((size_t)B_TOT * 4);

  prep_k<<<dim3(16, 16, 36), dim3(32, 8), 0, stream>>>(W0, Wt0, W1, Wt1, W2, Wt2, W3, Wt3,
                                                       U0, U0t, U1, U1t, U2, U2t, U3, U3t);
  bucket_k<<<1, NT_BUCKET, 0, stream>>>(y, offsets, perm);
  fused_k<<<NBLK, NTHR, 0, stream>>>(x, Wt0, b0, Wt1, b1, Wt2, b2, Wt3, b3,
                                     U0t, c0, U1t, c1, U2t, c2, U3t, c3,
                                     offsets, perm, out);
}